// Round 18
// baseline (843.793 us; speedup 1.0000x reference)
//
#include <hip/hip_runtime.h>
#include <math.h>

#define BB 4096
#define SS 10
#define EE 1536
#define HH 12
#define HDIM 128
#define MROWS (BB * SS)    // 40960 rows per branch
#define BB2 (2 * BB)       // both branches
#define MROWS2 (2 * MROWS)

typedef short short8 __attribute__((ext_vector_type(8)));
typedef float f32x4 __attribute__((ext_vector_type(4)));
typedef const unsigned char __attribute__((address_space(1))) gu8;
typedef unsigned char __attribute__((address_space(3))) lu8;

__device__ __forceinline__ unsigned short f2bf(float x) {
  unsigned int u = __float_as_uint(x);
  return (unsigned short)((u + 0x7FFFu + ((u >> 16) & 1u)) >> 16);
}
__device__ __forceinline__ float bf2f(unsigned short u) {
  return __uint_as_float(((unsigned int)u) << 16);
}

// ---- mask dtype detection (bool bytes vs int32 vs f32), grid-stride --------
__global__ void k_detect(const unsigned int* __restrict__ m, int* __restrict__ flags) {
  int lb = 0, lf = 0;
  int stride = gridDim.x * blockDim.x;
  for (int i = blockIdx.x * blockDim.x + threadIdx.x; i < BB * SS / 4; i += stride) {
    unsigned int wv = m[i];
    if ((wv >> 8) & 0xFFu) lb = 1;
    if (wv >> 16) lf = 1;
  }
  if (lb) atomicOr(&flags[0], 1);
  if (lf) atomicOr(&flags[1], 1);
}

__global__ void k_lastidx(const void* __restrict__ ma, const void* __restrict__ mb,
                          const int* __restrict__ flags, int* __restrict__ lastidx) {
  int idx = blockIdx.x * blockDim.x + threadIdx.x;
  if (idx >= BB2) return;
  const void* m = (idx >= BB) ? mb : ma;
  int b = idx & (BB - 1);
  int f = flags[0] ? 1 : (flags[1] ? 2 : 0);
  int len = 0;
  for (int s = 0; s < SS; ++s) {
    int j = b * SS + s;
    int pad;
    if (f == 1)      pad = ((const unsigned char*)m)[j] != 0;
    else if (f == 2) pad = ((const float*)m)[j] != 0.0f;
    else             pad = ((const int*)m)[j] != 0;
    len += (pad == 0);
  }
  lastidx[idx] = len - 1;
}

// ---- positional-encoding table --------------------------------------------
__global__ void k_pe(float* __restrict__ pe) {
  int idx = blockIdx.x * blockDim.x + threadIdx.x;
  if (idx >= SS * EE) return;
  int s = idx / EE, e = idx - (idx / EE) * EE;
  float fe = (float)(e & ~1);
  float freq = expf(fe * (-9.210340371976184f / (float)EE));  // -ln(10000)/E
  float arg = (float)s * freq;
  pe[idx] = (e & 1) ? cosf(arg) : sinf(arg);
}

// ---- weight transpose f32[K][N] -> bf16[N][K]; z==5: straight cast of kw ---
__global__ void k_trans(const float* __restrict__ w0, const float* __restrict__ w1,
                        const float* __restrict__ w2, const float* __restrict__ w3,
                        const float* __restrict__ w4, unsigned short* __restrict__ wt,
                        unsigned short* __restrict__ kwb) {
  __shared__ float tile[32][33];
  int z = blockIdx.z;
  int n0 = blockIdx.x * 32, k0 = blockIdx.y * 32;
  int tx = threadIdx.x, ty = threadIdx.y;
  if (z == 5) {  // layout-preserving bf16 cast of Wk into kwb
#pragma unroll
    for (int i = 0; i < 4; ++i) {
      size_t idx = (size_t)(k0 + ty + i * 8) * EE + n0 + tx;
      kwb[idx] = f2bf(w1[idx]);
    }
    return;
  }
  const float* W = z == 0 ? w0 : z == 1 ? w1 : z == 2 ? w2 : z == 3 ? w3 : w4;
  unsigned short* T = wt + (size_t)z * EE * EE;
#pragma unroll
  for (int i = 0; i < 4; ++i)
    tile[ty + i * 8][tx] = W[(size_t)(k0 + ty + i * 8) * EE + n0 + tx];
  __syncthreads();
#pragma unroll
  for (int i = 0; i < 4; ++i)
    T[(size_t)(n0 + ty + i * 8) * EE + k0 + tx] = f2bf(tile[tx][ty + i * 8]);
}

// ---- fused add-PE + LayerNorm: wave-per-row, single-pass, no LDS -----------
__global__ __launch_bounds__(256) void k_ln(
    const float* __restrict__ av, const float* __restrict__ bv,
    const float* __restrict__ pe,
    const float* __restrict__ g, const float* __restrict__ be,
    const int* __restrict__ lastidx,
    unsigned short* __restrict__ xln, unsigned short* __restrict__ lastx) {
  int w = threadIdx.x >> 6, lane = threadIdx.x & 63;
  int row = blockIdx.x * 4 + w;               // global row (both branches)
  const float* xin = (row < MROWS) ? (av + (size_t)row * EE)
                                   : (bv + (size_t)(row - MROWS) * EE);
  int bg = row / SS, s = row - bg * SS;       // bg in [0, 2*BB)
  const float4* x4 = (const float4*)xin;
  const float4* p4 = (const float4*)(pe + s * EE);
  float4 v[6];
  float s1 = 0.f, s2 = 0.f;
#pragma unroll
  for (int j = 0; j < 6; ++j) {
    float4 a = x4[j * 64 + lane], p = p4[j * 64 + lane];
    a.x += p.x; a.y += p.y; a.z += p.z; a.w += p.w;
    v[j] = a;
    s1 += a.x + a.y + a.z + a.w;
    s2 += a.x * a.x + a.y * a.y + a.z * a.z + a.w * a.w;
  }
#pragma unroll
  for (int off = 32; off; off >>= 1) {
    s1 += __shfl_xor(s1, off, 64);
    s2 += __shfl_xor(s2, off, 64);
  }
  float mu = s1 * (1.0f / EE);
  float var = s2 * (1.0f / EE) - mu * mu;
  float scl = rsqrtf(var + 1e-5f);
  bool isLast = (s == lastidx[bg]);
  uint2* orow = (uint2*)(xln + (size_t)row * EE);
  uint2* lrow = (uint2*)(lastx + (size_t)bg * EE);
  const float4* g4 = (const float4*)g;
  const float4* b4 = (const float4*)be;
#pragma unroll
  for (int j = 0; j < 6; ++j) {
    int idx = j * 64 + lane;
    float4 gg = g4[idx], bb = b4[idx];
    float o0 = (v[j].x - mu) * scl * gg.x + bb.x;
    float o1 = (v[j].y - mu) * scl * gg.y + bb.y;
    float o2 = (v[j].z - mu) * scl * gg.z + bb.z;
    float o3 = (v[j].w - mu) * scl * gg.w + bb.w;
    uint2 pk;
    pk.x = (unsigned int)f2bf(o0) | ((unsigned int)f2bf(o1) << 16);
    pk.y = (unsigned int)f2bf(o2) | ((unsigned int)f2bf(o3) << 16);
    orow[idx] = pk;
    if (isLast) lrow[idx] = pk;
  }
}

// ---- specialized K=128 single-stage GEMM for the qk projection --------------
// qky[b][h*EE+e] = sum_d qbuf[b][h*128+d] * kwb[e][h*128+d], per plane h.
// Whole K staged at once; ONE barrier per block; 64 MFMAs/wave. XOR slot
// swizzle: linear gload_lds dest + inverse-swizzled global source + swizzled
// read.
__global__ __launch_bounds__(256) void k_gemmqk(
    const unsigned short* __restrict__ A,   // qbuf [BB2][EE]
    const unsigned short* __restrict__ Bt,  // kwb  [EE][EE]
    unsigned short* __restrict__ C) {       // qky  [BB2][HH*EE]
  __shared__ __align__(16) unsigned char smA[32768];
  __shared__ __align__(16) unsigned char smB[32768];
  int h = blockIdx.y;
  int bid = blockIdx.x;
  int xcd = bid & 7, lin = bid >> 3;
  int mt = xcd * 8 + lin / 12;          // M=8192 -> 64 mtiles = 8 xcd x 8
  int nt = lin % 12;                    // N=1536 -> 12 ntiles
  int m0 = mt << 7, n0 = nt << 7;
  int t = threadIdx.x, wid = t >> 6, lane = t & 63;
  const unsigned char* Ab = (const unsigned char*)(A + (size_t)h * HDIM);
  const unsigned char* Bb = (const unsigned char*)(Bt + (size_t)h * HDIM);
  const size_t ldb = (size_t)EE * 2;    // 3072 bytes per row
#pragma unroll
  for (int i = 0; i < 8; ++i) {
    int idx = t + i * 256;
    int row = idx >> 4, slot = idx & 15;
    int srcb = ((slot ^ (row & 7)) << 4);
    int Lu = wid * 1024 + i * 4096;     // wave-uniform; HW adds lane*16
    __builtin_amdgcn_global_load_lds((gu8*)(Ab + (size_t)(m0 + row) * ldb + srcb),
                                     (lu8*)(smA + Lu), 16, 0, 0);
    __builtin_amdgcn_global_load_lds((gu8*)(Bb + (size_t)(n0 + row) * ldb + srcb),
                                     (lu8*)(smB + Lu), 16, 0, 0);
  }
  __syncthreads();
  int wm = wid >> 1, wn = wid & 1;
  int lrow = lane & 15, kgrp = lane >> 4;
  f32x4 acc[4][4] = {};
#pragma unroll
  for (int kk = 0; kk < 4; ++kk) {
    int phys = ((kk * 4 + kgrp) ^ (lrow & 7)) << 4;
    short8 af[4], bfr[4];
#pragma unroll
    for (int i = 0; i < 4; ++i) {
      af[i]  = *(const short8*)(smA + (wm * 64 + i * 16 + lrow) * 256 + phys);
      bfr[i] = *(const short8*)(smB + (wn * 64 + i * 16 + lrow) * 256 + phys);
    }
#pragma unroll
    for (int mi = 0; mi < 4; ++mi)
#pragma unroll
      for (int ni = 0; ni < 4; ++ni)
        acc[mi][ni] = __builtin_amdgcn_mfma_f32_16x16x32_bf16(af[mi], bfr[ni], acc[mi][ni], 0, 0, 0);
  }
  int rbase = m0 + wm * 64 + (lane >> 4) * 4;
  int cbase = n0 + wn * 64 + (lane & 15);
#pragma unroll
  for (int mi = 0; mi < 4; ++mi)
#pragma unroll
    for (int ni = 0; ni < 4; ++ni) {
      int c = cbase + ni * 16;
#pragma unroll
      for (int j = 0; j < 4; ++j) {
        int r = rbase + mi * 16 + j;
        C[(size_t)r * (HH * EE) + (size_t)h * EE + c] = f2bf(acc[mi][ni][j]);
      }
    }
}

// ---- specialized ctx GEMM: per plane h, [8192x1536]@[1536x128] + bias ------
// ctx[b][h*128+c] = sum_e qky[b][h*EE+e] * wt_v[h*HDIM*EE + c*EE + e] + vbs.
// A staged in LDS with BK=64 (16 KB, XOR-slot swizzle, 48 barriers vs 96);
// B read DIRECTLY from global (384 KB/plane, L2-resident across the plane's
// 64 m-blocks — same discipline as attn2's qk reads).
__global__ __launch_bounds__(256) void k_gemmctx(
    const unsigned short* __restrict__ A,   // qky [BB2][HH*EE]
    const unsigned short* __restrict__ Bt,  // wt_v [n=h*128+c][k=e]
    const float* __restrict__ bias,         // vbs [EE]
    unsigned short* __restrict__ C) {       // ctx [BB2][EE]
  __shared__ __align__(16) unsigned char smA[16384];
  int h = blockIdx.y;
  const unsigned char* Ab = (const unsigned char*)(A + (size_t)h * EE);
  const unsigned short* Bv = Bt + (size_t)h * HDIM * EE;
  const float* bi = bias + (size_t)h * HDIM;
  int bid = blockIdx.x;
  int xcd = bid & 7, lin = bid >> 3;
  int mt = xcd * 8 + lin;               // 64 m-tiles
  int m0 = mt << 7;
  int t = threadIdx.x, wid = t >> 6, lane = t & 63;
  int wm = wid >> 1, wn = wid & 1;
  const size_t ldaB = (size_t)(HH * EE) * 2;
  int lrow = lane & 15, kgrp = lane >> 4;
  f32x4 acc[4][4] = {};
  for (int kt = 0; kt < 24; ++kt) {
    int k0b = kt << 7;                  // 64 elems * 2B per chunk
#pragma unroll
    for (int i = 0; i < 4; ++i) {
      int idx = t + i * 256;
      int row = idx >> 3, slot = idx & 7;
      int srcb = ((slot ^ (row & 7)) << 4);
      int Lu = wid * 1024 + i * 4096;
      __builtin_amdgcn_global_load_lds((gu8*)(Ab + (size_t)(m0 + row) * ldaB + k0b + srcb),
                                       (lu8*)(smA + Lu), 16, 0, 0);
    }
    __syncthreads();
#pragma unroll
    for (int kk = 0; kk < 2; ++kk) {
      short8 af[4], bfr[4];
#pragma unroll
      for (int i = 0; i < 4; ++i) {
        int arow = wm * 64 + i * 16 + lrow;
        int slot = kk * 4 + kgrp;
        af[i]  = *(const short8*)(smA + arow * 128 + ((slot ^ (arow & 7)) << 4));
        bfr[i] = *(const short8*)(Bv + (size_t)(wn * 64 + i * 16 + lrow) * EE +
                                  kt * 64 + kk * 32 + kgrp * 8);
      }
#pragma unroll
      for (int mi = 0; mi < 4; ++mi)
#pragma unroll
        for (int ni = 0; ni < 4; ++ni)
          acc[mi][ni] = __builtin_amdgcn_mfma_f32_16x16x32_bf16(af[mi], bfr[ni], acc[mi][ni], 0, 0, 0);
    }
    __syncthreads();
  }
  int rbase = m0 + wm * 64 + (lane >> 4) * 4;
  int cbase = wn * 64 + (lane & 15);
#pragma unroll
  for (int mi = 0; mi < 4; ++mi)
#pragma unroll
    for (int ni = 0; ni < 4; ++ni) {
      int c = cbase + ni * 16;
      float bv = bi[c];
#pragma unroll
      for (int j = 0; j < 4; ++j) {
        int r = rbase + mi * 16 + j;
        C[(size_t)r * EE + h * HDIM + c] = f2bf(acc[mi][ni][j] + bv);
      }
    }
}

// ---- 256x256 8-phase bf16 GEMM (T1+T2+T3+T4+T5) ----------------------------
#define MMAQ(AR_, BR_, QM, QN)                                                  \
  do {                                                                          \
    _Pragma("unroll")                                                           \
    for (int mi_ = 0; mi_ < 4; ++mi_) {                                         \
      _Pragma("unroll")                                                         \
      for (int ni_ = 0; ni_ < 2; ++ni_) {                                       \
        acc[(QM)*4 + mi_][(QN)*2 + ni_] = __builtin_amdgcn_mfma_f32_16x16x32_bf16( \
            AR_[mi_][0], BR_[ni_][0], acc[(QM)*4 + mi_][(QN)*2 + ni_], 0, 0, 0);   \
        acc[(QM)*4 + mi_][(QN)*2 + ni_] = __builtin_amdgcn_mfma_f32_16x16x32_bf16( \
            AR_[mi_][1], BR_[ni_][1], acc[(QM)*4 + mi_][(QN)*2 + ni_], 0, 0, 0);   \
      }                                                                         \
    }                                                                           \
  } while (0)

#define PHASE_MID()                                      \
  do {                                                   \
    __builtin_amdgcn_s_barrier();                        \
    asm volatile("s_waitcnt lgkmcnt(0)" ::: "memory");   \
    __builtin_amdgcn_s_setprio(1);                       \
  } while (0)
#define PHASE_END()                                      \
  do {                                                   \
    __builtin_amdgcn_s_setprio(0);                       \
    __builtin_amdgcn_s_barrier();                        \
  } while (0)

template<int EPI>
__global__ __launch_bounds__(512, 2) void k_gemm256(
    const unsigned short* __restrict__ A, const unsigned short* __restrict__ Bt,
    const float* __restrict__ bias,
    void* __restrict__ C, int M, int N, int K) {
  __shared__ __align__(16) unsigned char lds[131072];
  const int NT = K >> 6;
  const int niters = NT >> 1;
  const int Ntiles = N >> 8;
  const int perx = (M >> 8) >> 3;
  const int MTG = 4;
  int bid = blockIdx.x;
  int xcd = bid & 7, lin = bid >> 3;
  int grp = lin / (MTG * Ntiles);
  int rem = lin - grp * (MTG * Ntiles);
  int nt = rem / MTG, mi_ = rem - nt * MTG;
  int mt = xcd * perx + grp * MTG + mi_;
  int m0 = mt << 8, n0 = nt << 8;
  int tid = threadIdx.x;
  int w = tid >> 6, lane = tid & 63;
  int wm = w >> 2, wn = w & 3;
  const size_t lda = (size_t)K * 2;
  const unsigned char* Ag = (const unsigned char*)A;
  const unsigned char* Bg = (const unsigned char*)Bt;

  unsigned char* A0 = lds;
  unsigned char* B0 = lds + 32768;
  unsigned char* A1 = lds + 65536;
  unsigned char* B1 = lds + 98304;

  int lrows = lane >> 3;
  int colswz = (((lane & 7) ^ (lrows & 7)) << 4);
  int rowA = w * 8;
  int rowB = (w >> 2) * 64 + (w & 3) * 8;

  auto stageA = [&](unsigned char* ldsA, int q, int kt) {
    int cb = kt * 128 + colswz;
#pragma unroll
    for (int i = 0; i < 2; ++i) {
      int tr = q * 64 + i * 128 + rowA;
      __builtin_amdgcn_global_load_lds(
          (gu8*)(Ag + (size_t)(m0 + tr + lrows) * lda + cb),
          (lu8*)(ldsA + tr * 128), 16, 0, 0);
    }
  };
  auto stageB = [&](unsigned char* ldsB, int q, int kt) {
    int cb = kt * 128 + colswz;
#pragma unroll
    for (int i = 0; i < 2; ++i) {
      int tr = q * 32 + i * 128 + rowB;
      __builtin_amdgcn_global_load_lds(
          (gu8*)(Bg + (size_t)(n0 + tr + lrows) * lda + cb),
          (lu8*)(ldsB + tr * 128), 16, 0, 0);
    }
  };

  int lrow = lane & 15, kgrp = lane >> 4, r7 = lane & 7;
  int s0 = ((kgrp ^ r7) << 4), s1 = (((kgrp | 4) ^ r7) << 4);
  int abase = (wm * 128 + lrow) * 128;
  int bbase = (wn * 64 + lrow) * 128;

  short8 ar[4][2], br0[2][2], br1[2][2];
  f32x4 acc[8][4];
#pragma unroll
  for (int i = 0; i < 8; ++i)
#pragma unroll
    for (int j = 0; j < 4; ++j) acc[i][j] = (f32x4)0.f;

  auto ldA = [&](unsigned char* ldsA, int qm) {
#pragma unroll
    for (int mi2 = 0; mi2 < 4; ++mi2) {
      ar[mi2][0] = *(const short8*)(ldsA + abase + qm * 8192 + mi2 * 2048 + s0);
      ar[mi2][1] = *(const short8*)(ldsA + abase + qm * 8192 + mi2 * 2048 + s1);
    }
  };
  auto ldB = [&](unsigned char* ldsB, int qn, short8 (&br)[2][2]) {
#pragma unroll
    for (int ni2 = 0; ni2 < 2; ++ni2) {
      br[ni2][0] = *(const short8*)(ldsB + bbase + qn * 4096 + ni2 * 2048 + s0);
      br[ni2][1] = *(const short8*)(ldsB + bbase + qn * 4096 + ni2 * 2048 + s1);
    }
  };

  stageA(A0, 0, 0); stageB(B0, 0, 0); stageA(A0, 1, 0); stageB(B0, 1, 0);
  stageA(A1, 0, 1); stageB(B1, 0, 1);
  asm volatile("s_waitcnt vmcnt(8)" ::: "memory");
  __builtin_amdgcn_s_barrier();

  for (int it = 0; it < niters - 1; ++it) {
    int t1 = 2 * it + 1, t2 = 2 * it + 2, t3 = 2 * it + 3;
    ldA(A0, 0); ldB(B0, 0, br0);
    stageA(A1, 1, t1);
    asm volatile("s_waitcnt vmcnt(6)" ::: "memory");
    PHASE_MID(); MMAQ(ar, br0, 0, 0); PHASE_END();
    ldB(B0, 1, br1);
    stageB(B1, 1, t1);
    PHASE_MID(); MMAQ(ar, br1, 0, 1); PHASE_END();
    ldA(A0, 1);
    stageA(A0, 0, t2);
    PHASE_MID(); MMAQ(ar, br0, 1, 0); PHASE_END();
    stageB(B0, 0, t2);
    asm volatile("s_waitcnt vmcnt(8)" ::: "memory");
    PHASE_MID(); MMAQ(ar, br1, 1, 1); PHASE_END();
    ldA(A1, 0); ldB(B1, 0, br0);
    stageA(A0, 1, t2);
    asm volatile("s_waitcnt vmcnt(6)" ::: "memory");
    PHASE_MID(); MMAQ(ar, br0, 0, 0); PHASE_END();
    ldB(B1, 1, br1);
    stageB(B0, 1, t2);
    PHASE_MID(); MMAQ(ar, br1, 0, 1); PHASE_END();
    ldA(A1, 1);
    if (t3 < NT) stageA(A1, 0, t3);
    PHASE_MID(); MMAQ(ar, br0, 1, 0); PHASE_END();
    if (t3 < NT) stageB(B1, 0, t3);
    asm volatile("s_waitcnt vmcnt(8)" ::: "memory");
    PHASE_MID(); MMAQ(ar, br1, 1, 1); PHASE_END();
  }
  {
    int t1 = NT - 1;
    ldA(A0, 0); ldB(B0, 0, br0);
    stageA(A1, 1, t1);
    asm volatile("s_waitcnt vmcnt(6)" ::: "memory");
    PHASE_MID(); MMAQ(ar, br0, 0, 0); PHASE_END();
    ldB(B0, 1, br1);
    stageB(B1, 1, t1);
    PHASE_MID(); MMAQ(ar, br1, 0, 1); PHASE_END();
    ldA(A0, 1);
    PHASE_MID(); MMAQ(ar, br0, 1, 0); PHASE_END();
    asm volatile("s_waitcnt vmcnt(4)" ::: "memory");
    PHASE_MID(); MMAQ(ar, br1, 1, 1); PHASE_END();
    ldA(A1, 0); ldB(B1, 0, br0);
    asm volatile("s_waitcnt vmcnt(2)" ::: "memory");
    PHASE_MID(); MMAQ(ar, br0, 0, 0); PHASE_END();
    ldB(B1, 1, br1);
    asm volatile("s_waitcnt vmcnt(0)" ::: "memory");
    PHASE_MID(); MMAQ(ar, br1, 0, 1); PHASE_END();
    ldA(A1, 1);
    PHASE_MID(); MMAQ(ar, br0, 1, 0); PHASE_END();
    PHASE_MID(); MMAQ(ar, br1, 1, 1); PHASE_END();
  }

  int rb = m0 + wm * 128 + (lane >> 4) * 4;
  int cb2 = n0 + wn * 64 + (lane & 15);
#pragma unroll
  for (int fm = 0; fm < 8; ++fm)
#pragma unroll
    for (int fn = 0; fn < 4; ++fn) {
      int c = cb2 + fn * 16;
      float bv = bias[c];
#pragma unroll
      for (int j = 0; j < 4; ++j) {
        int r = rb + fm * 16 + j;
        float val = acc[fm][fn][j] + bv;
        if (EPI == 2) {
          val = 0.5f * val * (1.0f + erff(val * 0.7071067811865476f));
          ((float*)C)[(size_t)r * N + c] = val;
        } else {
          ((unsigned short*)C)[(size_t)r * N + c] = f2bf(val);
        }
      }
    }
}

// ---- fused scores + softmax + weighted-sum (round-9 proven structure) ------
__global__ __launch_bounds__(256) void k_attn2(
    const unsigned short* __restrict__ xln,   // [2*MROWS][EE]
    unsigned short* qky,                      // [2*BB][HH*EE]  in: qk, out: y
    const int* __restrict__ lastidx) {        // [2*BB]
  __shared__ __align__(16) unsigned short xs[10 * 1544];
  __shared__ float swp[4 * 256];
  __shared__ float wsm[120];
  int b = (BB2 - 1) - blockIdx.x;             // reverse: L3-warm qk first
  int t = threadIdx.x;
  const unsigned short* xg = xln + (size_t)b * SS * EE;
  unsigned short* qg = qky + (size_t)b * HH * EE;
#pragma unroll
  for (int j = 0; j < 8; ++j) {
    int idx = t + j * 256;
    if (idx < 1920) {
      int row = idx / 192, col = (idx - row * 192) * 8;
      *(short8*)(xs + row * 1544 + col) = *(const short8*)(xg + row * 1536 + col);
    }
  }
  __syncthreads();
  int w = t >> 6, lane = t & 63;
  int li = lastidx[b];
  // scores: one 16x16 tile, K=1536 split across 4 waves; A from global qk
  {
    int hr = lane & 15; if (hr > 11) hr = 11;   // A row (head), clamp
    int sr = lane & 15; if (sr > 9) sr = 9;     // B row (seq), clamp
    int kg = lane >> 4;
    f32x4 pacc = (f32x4)0.f;
#pragma unroll 4
    for (int kt = 0; kt < 12; ++kt) {
      int k0 = w * 384 + kt * 32 + kg * 8;
      short8 a  = *(const short8*)(qg + hr * 1536 + k0);
      short8 bf = *(const short8*)(xs + sr * 1544 + k0);
      pacc = __builtin_amdgcn_mfma_f32_16x16x32_bf16(a, bf, pacc, 0, 0, 0);
    }
    int prow = (lane >> 4) * 4, pcol = lane & 15;
#pragma unroll
    for (int j = 0; j < 4; ++j)
      swp[w * 256 + (prow + j) * 16 + pcol] = pacc[j];
  }
  __syncthreads();
  if (t < 120) {
    int h = t / 10, s = t - (t / 10) * 10;
    float v = swp[h * 16 + s] + swp[256 + h * 16 + s] +
              swp[512 + h * 16 + s] + swp[768 + h * 16 + s];
    wsm[t] = v * 0.08838834764831845f;  // HD^-0.5
  }
  __syncthreads();
  if (t < 12) {
    float mx = -1e30f;
    for (int s = 0; s <= li; ++s) mx = fmaxf(mx, wsm[t * 10 + s]);
    float sum = 0.f;
    float ex[SS];
    for (int s = 0; s <= li; ++s) {
      ex[s] = expf(wsm[t * 10 + s] - mx);
      sum += ex[s];
    }
    float inv = 1.0f / sum;
    for (int s = 0; s <= li; ++s) wsm[t * 10 + s] = ex[s] * inv;
  }
  __syncthreads();
  // y phase: wave w handles heads 3w..3w+2; x from LDS, all 10 s-terms
  // unconditional (invalid s has weight 0) -> independent loads.
  float wv[3][10];
#pragma unroll
  for (int hl = 0; hl < 3; ++hl)
#pragma unroll
    for (int s = 0; s < 10; ++s)
      wv[hl][s] = (s <= li) ? wsm[(3 * w + hl) * 10 + s] : 0.f;
#pragma unroll 2
  for (int pass = 0; pass < 12; ++pass) {
    int e0 = pass * 128 + lane * 2;
    unsigned int xr[10];
#pragma unroll
    for (int s = 0; s < 10; ++s)
      xr[s] = *(const unsigned int*)(xs + s * 1544 + e0);
    float acc[3][2] = {};
#pragma unroll
    for (int s = 0; s < 10; ++s) {
      float xlo = bf2f((unsigned short)(xr[s] & 0xffff));
      float xhi = bf2f((unsigned short)(xr[s] >> 16));
#pragma unroll
      for (int hl = 0; hl < 3; ++hl) {
        acc[hl][0] += wv[hl][s] * xlo;
        acc[hl][1] += wv[hl][s] * xhi;
      }
    }
#pragma unroll
    for (int hl = 0; hl < 3; ++hl) {
      unsigned int pk = (unsigned int)f2bf(acc[hl][0]) | ((unsigned int)f2bf(acc[hl][1]) << 16);
      *(unsigned int*)(qg + (3 * w + hl) * 1536 + e0) = pk;
    }
  }
}

extern "C" void kernel_launch(void* const* d_in, const int* in_sizes, int n_in,
                              void* d_out, int out_size, void* d_ws, size_t ws_size,
                              hipStream_t stream) {
  (void)in_sizes; (void)n_in; (void)out_size; (void)ws_size;
  const float* av  = (const float*)d_in[0];
  const float* bv  = (const float*)d_in[1];
  const void*  ma  = d_in[2];
  const void*  mb  = d_in[3];
  const float* qw  = (const float*)d_in[4];
  const float* qb  = (const float*)d_in[5];
  const float* kw  = (const float*)d_in[6];
  const float* kb  = (const float*)d_in[7];  (void)kb;  // softmax-invariant, dropped
  const float* vw  = (const float*)d_in[8];
  const float* vbs = (const float*)d_in[9];
  const float* ow  = (const float*)d_in[10];
  const float* ob  = (const float*)d_in[11];
  const float* fw  = (const float*)d_in[12];
  const float* fbs = (const float*)d_in[13];
  const float* lng = (const float*)d_in[14];
  const float* lnb = (const float*)d_in[15];

  unsigned char* ws = (unsigned char*)d_ws;
  size_t off = 0;
  auto alloc = [&](size_t bytes) {
    size_t r = off; off = (off + bytes + 255) & ~(size_t)255; return (void*)(ws + r);
  };
  int* flags            = (int*)alloc(8);
  float* pe             = (float*)alloc((size_t)SS * EE * 4);
  unsigned short* wt    = (unsigned short*)alloc((size_t)5 * EE * EE * 2);
  unsigned short* kwb   = (unsigned short*)alloc((size_t)EE * EE * 2);   // Wk bf16, [in][out]
  int* lastidx          = (int*)alloc((size_t)BB2 * 4);
  unsigned short* xln   = (unsigned short*)alloc((size_t)MROWS2 * EE * 2);     // 252 MB
  unsigned short* lastx = (unsigned short*)alloc((size_t)BB2 * EE * 2);        // 25 MB
  unsigned short* qbuf  = (unsigned short*)alloc((size_t)BB2 * EE * 2);        // 25 MB
  unsigned short* qky   = (unsigned short*)alloc((size_t)BB2 * HH * EE * 2);   // 302 MB
  unsigned short* ctx   = (unsigned short*)alloc((size_t)BB2 * EE * 2);        // 25 MB
  unsigned short* o1    = (unsigned short*)alloc((size_t)BB2 * EE * 2);        // 25 MB

  unsigned short* wt_q = wt;
  unsigned short* wt_v = wt + (size_t)2 * EE * EE;
  unsigned short* wt_o = wt + (size_t)3 * EE * EE;
  unsigned short* wt_f = wt + (size_t)4 * EE * EE;

  hipMemsetAsync(flags, 0, 8, stream);
  k_detect<<<40, 256, 0, stream>>>((const unsigned int*)ma, flags);
  k_pe<<<(SS * EE + 255) / 256, 256, 0, stream>>>(pe);
  k_trans<<<dim3(EE / 32, EE / 32, 6), dim3(32, 8), 0, stream>>>(qw, kw, vw, ow, fw, wt, kwb);
  k_lastidx<<<(BB2 + 255) / 256, 256, 0, stream>>>(ma, mb, flags, lastidx);

  // fused add-PE + LN, both branches: wave-per-row, 4 rows/block
  k_ln<<<MROWS2 / 4, 256, 0, stream>>>(av, bv, pe, lng, lnb, lastidx, xln, lastx);
  // Q projection: q = lastx @ Wq + qb   [8192 x 1536], 8-phase 256^2
  k_gemm256<0><<<(BB2 / 256) * (EE / 256), 512, 0, stream>>>(
      lastx, wt_q, qb, qbuf, BB2, EE, EE);
  // qk[b,h][e] = sum_d q[b,h,d] * Wk[e, h*128+d]  — single-stage K=128 kernel
  k_gemmqk<<<dim3(64 * 12, HH), 256, 0, stream>>>(qbuf, kwb, qky);
  // scores + softmax + weighted sum -> y (in place over qky), both branches
  k_attn2<<<BB2, 256, 0, stream>>>(xln, qky, lastidx);
  // ctx[b,hblk] = y[b,h] @ Wv[:,hblk] + bv  — specialized kernel, B from L2
  k_gemmctx<<<dim3(64, HH), 256, 0, stream>>>(qky, wt_v, vbs, ctx);
  // O projection: [8192 x 1536], 8-phase 256^2
  k_gemm256<0><<<(BB2 / 256) * (EE / 256), 512, 0, stream>>>(
      ctx, wt_o, ob, o1, BB2, EE, EE);
  // F projection + exact GELU -> f32 output (branch-major)
  k_gemm256<2><<<(BB2 / 256) * (EE / 256), 512, 0, stream>>>(
      o1, wt_f, fbs, d_out, BB2, EE, EE);
}

// Round 19
// 805.836 us; speedup vs baseline: 1.0471x; 1.0471x over previous
//
#include <hip/hip_runtime.h>
#include <math.h>

#define BB 4096
#define SS 10
#define EE 1536
#define HH 12
#define HDIM 128
#define MROWS (BB * SS)    // 40960 rows per branch
#define BB2 (2 * BB)       // both branches
#define MROWS2 (2 * MROWS)

typedef short short8 __attribute__((ext_vector_type(8)));
typedef float f32x4 __attribute__((ext_vector_type(4)));
typedef const unsigned char __attribute__((address_space(1))) gu8;
typedef unsigned char __attribute__((address_space(3))) lu8;

__device__ __forceinline__ unsigned short f2bf(float x) {
  unsigned int u = __float_as_uint(x);
  return (unsigned short)((u + 0x7FFFu + ((u >> 16) & 1u)) >> 16);
}
__device__ __forceinline__ float bf2f(unsigned short u) {
  return __uint_as_float(((unsigned int)u) << 16);
}

// ---- mask dtype detection (bool bytes vs int32 vs f32), grid-stride --------
__global__ void k_detect(const unsigned int* __restrict__ m, int* __restrict__ flags) {
  int lb = 0, lf = 0;
  int stride = gridDim.x * blockDim.x;
  for (int i = blockIdx.x * blockDim.x + threadIdx.x; i < BB * SS / 4; i += stride) {
    unsigned int wv = m[i];
    if ((wv >> 8) & 0xFFu) lb = 1;
    if (wv >> 16) lf = 1;
  }
  if (lb) atomicOr(&flags[0], 1);
  if (lf) atomicOr(&flags[1], 1);
}

__global__ void k_lastidx(const void* __restrict__ ma, const void* __restrict__ mb,
                          const int* __restrict__ flags, int* __restrict__ lastidx) {
  int idx = blockIdx.x * blockDim.x + threadIdx.x;
  if (idx >= BB2) return;
  const void* m = (idx >= BB) ? mb : ma;
  int b = idx & (BB - 1);
  int f = flags[0] ? 1 : (flags[1] ? 2 : 0);
  int len = 0;
  for (int s = 0; s < SS; ++s) {
    int j = b * SS + s;
    int pad;
    if (f == 1)      pad = ((const unsigned char*)m)[j] != 0;
    else if (f == 2) pad = ((const float*)m)[j] != 0.0f;
    else             pad = ((const int*)m)[j] != 0;
    len += (pad == 0);
  }
  lastidx[idx] = len - 1;
}

// ---- positional-encoding table --------------------------------------------
__global__ void k_pe(float* __restrict__ pe) {
  int idx = blockIdx.x * blockDim.x + threadIdx.x;
  if (idx >= SS * EE) return;
  int s = idx / EE, e = idx - (idx / EE) * EE;
  float fe = (float)(e & ~1);
  float freq = expf(fe * (-9.210340371976184f / (float)EE));  // -ln(10000)/E
  float arg = (float)s * freq;
  pe[idx] = (e & 1) ? cosf(arg) : sinf(arg);
}

// ---- weight transpose f32[K][N] -> bf16[N][K]; z==5: straight cast of kw ---
__global__ void k_trans(const float* __restrict__ w0, const float* __restrict__ w1,
                        const float* __restrict__ w2, const float* __restrict__ w3,
                        const float* __restrict__ w4, unsigned short* __restrict__ wt,
                        unsigned short* __restrict__ kwb) {
  __shared__ float tile[32][33];
  int z = blockIdx.z;
  int n0 = blockIdx.x * 32, k0 = blockIdx.y * 32;
  int tx = threadIdx.x, ty = threadIdx.y;
  if (z == 5) {  // layout-preserving bf16 cast of Wk into kwb
#pragma unroll
    for (int i = 0; i < 4; ++i) {
      size_t idx = (size_t)(k0 + ty + i * 8) * EE + n0 + tx;
      kwb[idx] = f2bf(w1[idx]);
    }
    return;
  }
  const float* W = z == 0 ? w0 : z == 1 ? w1 : z == 2 ? w2 : z == 3 ? w3 : w4;
  unsigned short* T = wt + (size_t)z * EE * EE;
#pragma unroll
  for (int i = 0; i < 4; ++i)
    tile[ty + i * 8][tx] = W[(size_t)(k0 + ty + i * 8) * EE + n0 + tx];
  __syncthreads();
#pragma unroll
  for (int i = 0; i < 4; ++i)
    T[(size_t)(n0 + ty + i * 8) * EE + k0 + tx] = f2bf(tile[tx][ty + i * 8]);
}

// ---- fused add-PE + LayerNorm: wave-per-row, single-pass, no LDS -----------
__global__ __launch_bounds__(256) void k_ln(
    const float* __restrict__ av, const float* __restrict__ bv,
    const float* __restrict__ pe,
    const float* __restrict__ g, const float* __restrict__ be,
    const int* __restrict__ lastidx,
    unsigned short* __restrict__ xln, unsigned short* __restrict__ lastx) {
  int w = threadIdx.x >> 6, lane = threadIdx.x & 63;
  int row = blockIdx.x * 4 + w;               // global row (both branches)
  const float* xin = (row < MROWS) ? (av + (size_t)row * EE)
                                   : (bv + (size_t)(row - MROWS) * EE);
  int bg = row / SS, s = row - bg * SS;       // bg in [0, 2*BB)
  const float4* x4 = (const float4*)xin;
  const float4* p4 = (const float4*)(pe + s * EE);
  float4 v[6];
  float s1 = 0.f, s2 = 0.f;
#pragma unroll
  for (int j = 0; j < 6; ++j) {
    float4 a = x4[j * 64 + lane], p = p4[j * 64 + lane];
    a.x += p.x; a.y += p.y; a.z += p.z; a.w += p.w;
    v[j] = a;
    s1 += a.x + a.y + a.z + a.w;
    s2 += a.x * a.x + a.y * a.y + a.z * a.z + a.w * a.w;
  }
#pragma unroll
  for (int off = 32; off; off >>= 1) {
    s1 += __shfl_xor(s1, off, 64);
    s2 += __shfl_xor(s2, off, 64);
  }
  float mu = s1 * (1.0f / EE);
  float var = s2 * (1.0f / EE) - mu * mu;
  float scl = rsqrtf(var + 1e-5f);
  bool isLast = (s == lastidx[bg]);
  uint2* orow = (uint2*)(xln + (size_t)row * EE);
  uint2* lrow = (uint2*)(lastx + (size_t)bg * EE);
  const float4* g4 = (const float4*)g;
  const float4* b4 = (const float4*)be;
#pragma unroll
  for (int j = 0; j < 6; ++j) {
    int idx = j * 64 + lane;
    float4 gg = g4[idx], bb = b4[idx];
    float o0 = (v[j].x - mu) * scl * gg.x + bb.x;
    float o1 = (v[j].y - mu) * scl * gg.y + bb.y;
    float o2 = (v[j].z - mu) * scl * gg.z + bb.z;
    float o3 = (v[j].w - mu) * scl * gg.w + bb.w;
    uint2 pk;
    pk.x = (unsigned int)f2bf(o0) | ((unsigned int)f2bf(o1) << 16);
    pk.y = (unsigned int)f2bf(o2) | ((unsigned int)f2bf(o3) << 16);
    orow[idx] = pk;
    if (isLast) lrow[idx] = pk;
  }
}

// ---- generalized 128x128 m97-structure bf16 GEMM ---------------------------
__global__ __launch_bounds__(256) void k_gemm_g(
    const unsigned short* __restrict__ A, int aStrH, int lda,
    const unsigned short* __restrict__ Bt, int bStrH, int ldb,
    const float* __restrict__ bias, int biasStrH,
    void* __restrict__ C, int cStrH, int ldc,
    int MB, int NB, int K) {
  __shared__ __align__(16) unsigned char smA[8192];
  __shared__ __align__(16) unsigned char smB[8192];
  int h = blockIdx.y;
  const unsigned char* Ab = (const unsigned char*)(A + (size_t)h * aStrH);
  const unsigned char* Bb = (const unsigned char*)(Bt + (size_t)h * bStrH);
  const float* bi = bias ? bias + (size_t)h * biasStrH : nullptr;
  int per = MB >> 3;
  int bid = blockIdx.x;
  int xcd = bid & 7, lin = bid >> 3;
  int mt = xcd * per + lin / NB;
  int nt = lin % NB;
  int m0 = mt << 7, n0 = nt << 7;
  int tid = threadIdx.x, wid = tid >> 6, lane = tid & 63;
  int wm = wid >> 1, wn = wid & 1;
  f32x4 acc[4][4] = {};
  const size_t ldaB = (size_t)lda * 2, ldbB = (size_t)ldb * 2;
  int lrow = lane & 15, kgrp = lane >> 4;
  int aoff = (wm * 64 + lrow) * 64 + kgrp * 16;
  int boff = (wn * 64 + lrow) * 64 + kgrp * 16;
  int Lbase = wid * 1024 + lane * 16;
  const int nk = K >> 5;
  for (int kt = 0; kt < nk; ++kt) {
    int k0b = kt << 6;
#pragma unroll
    for (int issue = 0; issue < 2; ++issue) {
      int L = issue * 4096 + Lbase;
      int row = L >> 6, colb = L & 63;
      int Lu = issue * 4096 + wid * 1024;
      __builtin_amdgcn_global_load_lds((gu8*)(Ab + (size_t)(m0 + row) * ldaB + k0b + colb),
                                       (lu8*)(smA + Lu), 16, 0, 0);
      __builtin_amdgcn_global_load_lds((gu8*)(Bb + (size_t)(n0 + row) * ldbB + k0b + colb),
                                       (lu8*)(smB + Lu), 16, 0, 0);
    }
    __syncthreads();
    short8 af[4], bfr[4];
#pragma unroll
    for (int i = 0; i < 4; ++i) {
      af[i]  = *(const short8*)(smA + aoff + i * 1024);
      bfr[i] = *(const short8*)(smB + boff + i * 1024);
    }
#pragma unroll
    for (int mi = 0; mi < 4; ++mi)
#pragma unroll
      for (int ni = 0; ni < 4; ++ni)
        acc[mi][ni] = __builtin_amdgcn_mfma_f32_16x16x32_bf16(af[mi], bfr[ni], acc[mi][ni], 0, 0, 0);
    __syncthreads();
  }
  int rbase = m0 + wm * 64 + (lane >> 4) * 4;
  int cbase = n0 + wn * 64 + (lane & 15);
#pragma unroll
  for (int mi = 0; mi < 4; ++mi) {
#pragma unroll
    for (int ni = 0; ni < 4; ++ni) {
      int c = cbase + ni * 16;
      float bv = bi ? bi[c] : 0.f;
#pragma unroll
      for (int j = 0; j < 4; ++j) {
        int r = rbase + mi * 16 + j;
        float val = acc[mi][ni][j] + bv;
        ((unsigned short*)C)[(size_t)h * cStrH + (size_t)r * ldc + c] = f2bf(val);
      }
    }
  }
}

// ---- specialized K=128 single-stage GEMM for the qk projection --------------
// qky[b][h*EE+e] = sum_d qbuf[b][h*128+d] * kwb[e][h*128+d], per plane h.
// Whole K staged at once; ONE barrier per block; 64 MFMAs/wave. XOR slot
// swizzle: linear gload_lds dest + inverse-swizzled global source + swizzled
// read.
__global__ __launch_bounds__(256) void k_gemmqk(
    const unsigned short* __restrict__ A,   // qbuf [BB2][EE]
    const unsigned short* __restrict__ Bt,  // kwb  [EE][EE]
    unsigned short* __restrict__ C) {       // qky  [BB2][HH*EE]
  __shared__ __align__(16) unsigned char smA[32768];
  __shared__ __align__(16) unsigned char smB[32768];
  int h = blockIdx.y;
  int bid = blockIdx.x;
  int xcd = bid & 7, lin = bid >> 3;
  int mt = xcd * 8 + lin / 12;          // M=8192 -> 64 mtiles = 8 xcd x 8
  int nt = lin % 12;                    // N=1536 -> 12 ntiles
  int m0 = mt << 7, n0 = nt << 7;
  int t = threadIdx.x, wid = t >> 6, lane = t & 63;
  const unsigned char* Ab = (const unsigned char*)(A + (size_t)h * HDIM);
  const unsigned char* Bb = (const unsigned char*)(Bt + (size_t)h * HDIM);
  const size_t ldb = (size_t)EE * 2;    // 3072 bytes per row
#pragma unroll
  for (int i = 0; i < 8; ++i) {
    int idx = t + i * 256;
    int row = idx >> 4, slot = idx & 15;
    int srcb = ((slot ^ (row & 7)) << 4);
    int Lu = wid * 1024 + i * 4096;     // wave-uniform; HW adds lane*16
    __builtin_amdgcn_global_load_lds((gu8*)(Ab + (size_t)(m0 + row) * ldb + srcb),
                                     (lu8*)(smA + Lu), 16, 0, 0);
    __builtin_amdgcn_global_load_lds((gu8*)(Bb + (size_t)(n0 + row) * ldb + srcb),
                                     (lu8*)(smB + Lu), 16, 0, 0);
  }
  __syncthreads();
  int wm = wid >> 1, wn = wid & 1;
  int lrow = lane & 15, kgrp = lane >> 4;
  f32x4 acc[4][4] = {};
#pragma unroll
  for (int kk = 0; kk < 4; ++kk) {
    int phys = ((kk * 4 + kgrp) ^ (lrow & 7)) << 4;
    short8 af[4], bfr[4];
#pragma unroll
    for (int i = 0; i < 4; ++i) {
      af[i]  = *(const short8*)(smA + (wm * 64 + i * 16 + lrow) * 256 + phys);
      bfr[i] = *(const short8*)(smB + (wn * 64 + i * 16 + lrow) * 256 + phys);
    }
#pragma unroll
    for (int mi = 0; mi < 4; ++mi)
#pragma unroll
      for (int ni = 0; ni < 4; ++ni)
        acc[mi][ni] = __builtin_amdgcn_mfma_f32_16x16x32_bf16(af[mi], bfr[ni], acc[mi][ni], 0, 0, 0);
  }
  int rbase = m0 + wm * 64 + (lane >> 4) * 4;
  int cbase = n0 + wn * 64 + (lane & 15);
#pragma unroll
  for (int mi = 0; mi < 4; ++mi)
#pragma unroll
    for (int ni = 0; ni < 4; ++ni) {
      int c = cbase + ni * 16;
#pragma unroll
      for (int j = 0; j < 4; ++j) {
        int r = rbase + mi * 16 + j;
        C[(size_t)r * (HH * EE) + (size_t)h * EE + c] = f2bf(acc[mi][ni][j]);
      }
    }
}

// ---- 256x256 8-phase bf16 GEMM (T1+T2+T3+T4+T5) ----------------------------
#define MMAQ(AR_, BR_, QM, QN)                                                  \
  do {                                                                          \
    _Pragma("unroll")                                                           \
    for (int mi_ = 0; mi_ < 4; ++mi_) {                                         \
      _Pragma("unroll")                                                         \
      for (int ni_ = 0; ni_ < 2; ++ni_) {                                       \
        acc[(QM)*4 + mi_][(QN)*2 + ni_] = __builtin_amdgcn_mfma_f32_16x16x32_bf16( \
            AR_[mi_][0], BR_[ni_][0], acc[(QM)*4 + mi_][(QN)*2 + ni_], 0, 0, 0);   \
        acc[(QM)*4 + mi_][(QN)*2 + ni_] = __builtin_amdgcn_mfma_f32_16x16x32_bf16( \
            AR_[mi_][1], BR_[ni_][1], acc[(QM)*4 + mi_][(QN)*2 + ni_], 0, 0, 0);   \
      }                                                                         \
    }                                                                           \
  } while (0)

#define PHASE_MID()                                      \
  do {                                                   \
    __builtin_amdgcn_s_barrier();                        \
    asm volatile("s_waitcnt lgkmcnt(0)" ::: "memory");   \
    __builtin_amdgcn_s_setprio(1);                       \
  } while (0)
#define PHASE_END()                                      \
  do {                                                   \
    __builtin_amdgcn_s_setprio(0);                       \
    __builtin_amdgcn_s_barrier();                        \
  } while (0)

template<int EPI>
__global__ __launch_bounds__(512, 2) void k_gemm256(
    const unsigned short* __restrict__ A, const unsigned short* __restrict__ Bt,
    const float* __restrict__ bias,
    void* __restrict__ C, int M, int N, int K) {
  __shared__ __align__(16) unsigned char lds[131072];
  const int NT = K >> 6;
  const int niters = NT >> 1;
  const int Ntiles = N >> 8;
  const int perx = (M >> 8) >> 3;
  const int MTG = 4;
  int bid = blockIdx.x;
  int xcd = bid & 7, lin = bid >> 3;
  int grp = lin / (MTG * Ntiles);
  int rem = lin - grp * (MTG * Ntiles);
  int nt = rem / MTG, mi_ = rem - nt * MTG;
  int mt = xcd * perx + grp * MTG + mi_;
  int m0 = mt << 8, n0 = nt << 8;
  int tid = threadIdx.x;
  int w = tid >> 6, lane = tid & 63;
  int wm = w >> 2, wn = w & 3;
  const size_t lda = (size_t)K * 2;
  const unsigned char* Ag = (const unsigned char*)A;
  const unsigned char* Bg = (const unsigned char*)Bt;

  unsigned char* A0 = lds;
  unsigned char* B0 = lds + 32768;
  unsigned char* A1 = lds + 65536;
  unsigned char* B1 = lds + 98304;

  int lrows = lane >> 3;
  int colswz = (((lane & 7) ^ (lrows & 7)) << 4);
  int rowA = w * 8;
  int rowB = (w >> 2) * 64 + (w & 3) * 8;

  auto stageA = [&](unsigned char* ldsA, int q, int kt) {
    int cb = kt * 128 + colswz;
#pragma unroll
    for (int i = 0; i < 2; ++i) {
      int tr = q * 64 + i * 128 + rowA;
      __builtin_amdgcn_global_load_lds(
          (gu8*)(Ag + (size_t)(m0 + tr + lrows) * lda + cb),
          (lu8*)(ldsA + tr * 128), 16, 0, 0);
    }
  };
  auto stageB = [&](unsigned char* ldsB, int q, int kt) {
    int cb = kt * 128 + colswz;
#pragma unroll
    for (int i = 0; i < 2; ++i) {
      int tr = q * 32 + i * 128 + rowB;
      __builtin_amdgcn_global_load_lds(
          (gu8*)(Bg + (size_t)(n0 + tr + lrows) * lda + cb),
          (lu8*)(ldsB + tr * 128), 16, 0, 0);
    }
  };

  int lrow = lane & 15, kgrp = lane >> 4, r7 = lane & 7;
  int s0 = ((kgrp ^ r7) << 4), s1 = (((kgrp | 4) ^ r7) << 4);
  int abase = (wm * 128 + lrow) * 128;
  int bbase = (wn * 64 + lrow) * 128;

  short8 ar[4][2], br0[2][2], br1[2][2];
  f32x4 acc[8][4];
#pragma unroll
  for (int i = 0; i < 8; ++i)
#pragma unroll
    for (int j = 0; j < 4; ++j) acc[i][j] = (f32x4)0.f;

  auto ldA = [&](unsigned char* ldsA, int qm) {
#pragma unroll
    for (int mi2 = 0; mi2 < 4; ++mi2) {
      ar[mi2][0] = *(const short8*)(ldsA + abase + qm * 8192 + mi2 * 2048 + s0);
      ar[mi2][1] = *(const short8*)(ldsA + abase + qm * 8192 + mi2 * 2048 + s1);
    }
  };
  auto ldB = [&](unsigned char* ldsB, int qn, short8 (&br)[2][2]) {
#pragma unroll
    for (int ni2 = 0; ni2 < 2; ++ni2) {
      br[ni2][0] = *(const short8*)(ldsB + bbase + qn * 4096 + ni2 * 2048 + s0);
      br[ni2][1] = *(const short8*)(ldsB + bbase + qn * 4096 + ni2 * 2048 + s1);
    }
  };

  stageA(A0, 0, 0); stageB(B0, 0, 0); stageA(A0, 1, 0); stageB(B0, 1, 0);
  stageA(A1, 0, 1); stageB(B1, 0, 1);
  asm volatile("s_waitcnt vmcnt(8)" ::: "memory");
  __builtin_amdgcn_s_barrier();

  for (int it = 0; it < niters - 1; ++it) {
    int t1 = 2 * it + 1, t2 = 2 * it + 2, t3 = 2 * it + 3;
    ldA(A0, 0); ldB(B0, 0, br0);
    stageA(A1, 1, t1);
    asm volatile("s_waitcnt vmcnt(6)" ::: "memory");
    PHASE_MID(); MMAQ(ar, br0, 0, 0); PHASE_END();
    ldB(B0, 1, br1);
    stageB(B1, 1, t1);
    PHASE_MID(); MMAQ(ar, br1, 0, 1); PHASE_END();
    ldA(A0, 1);
    stageA(A0, 0, t2);
    PHASE_MID(); MMAQ(ar, br0, 1, 0); PHASE_END();
    stageB(B0, 0, t2);
    asm volatile("s_waitcnt vmcnt(8)" ::: "memory");
    PHASE_MID(); MMAQ(ar, br1, 1, 1); PHASE_END();
    ldA(A1, 0); ldB(B1, 0, br0);
    stageA(A0, 1, t2);
    asm volatile("s_waitcnt vmcnt(6)" ::: "memory");
    PHASE_MID(); MMAQ(ar, br0, 0, 0); PHASE_END();
    ldB(B1, 1, br1);
    stageB(B0, 1, t2);
    PHASE_MID(); MMAQ(ar, br1, 0, 1); PHASE_END();
    ldA(A1, 1);
    if (t3 < NT) stageA(A1, 0, t3);
    PHASE_MID(); MMAQ(ar, br0, 1, 0); PHASE_END();
    if (t3 < NT) stageB(B1, 0, t3);
    asm volatile("s_waitcnt vmcnt(8)" ::: "memory");
    PHASE_MID(); MMAQ(ar, br1, 1, 1); PHASE_END();
  }
  {
    int t1 = NT - 1;
    ldA(A0, 0); ldB(B0, 0, br0);
    stageA(A1, 1, t1);
    asm volatile("s_waitcnt vmcnt(6)" ::: "memory");
    PHASE_MID(); MMAQ(ar, br0, 0, 0); PHASE_END();
    ldB(B0, 1, br1);
    stageB(B1, 1, t1);
    PHASE_MID(); MMAQ(ar, br1, 0, 1); PHASE_END();
    ldA(A0, 1);
    PHASE_MID(); MMAQ(ar, br0, 1, 0); PHASE_END();
    asm volatile("s_waitcnt vmcnt(4)" ::: "memory");
    PHASE_MID(); MMAQ(ar, br1, 1, 1); PHASE_END();
    ldA(A1, 0); ldB(B1, 0, br0);
    asm volatile("s_waitcnt vmcnt(2)" ::: "memory");
    PHASE_MID(); MMAQ(ar, br0, 0, 0); PHASE_END();
    ldB(B1, 1, br1);
    asm volatile("s_waitcnt vmcnt(0)" ::: "memory");
    PHASE_MID(); MMAQ(ar, br1, 0, 1); PHASE_END();
    ldA(A1, 1);
    PHASE_MID(); MMAQ(ar, br0, 1, 0); PHASE_END();
    PHASE_MID(); MMAQ(ar, br1, 1, 1); PHASE_END();
  }

  int rb = m0 + wm * 128 + (lane >> 4) * 4;
  int cb2 = n0 + wn * 64 + (lane & 15);
#pragma unroll
  for (int fm = 0; fm < 8; ++fm)
#pragma unroll
    for (int fn = 0; fn < 4; ++fn) {
      int c = cb2 + fn * 16;
      float bv = bias[c];
#pragma unroll
      for (int j = 0; j < 4; ++j) {
        int r = rb + fm * 16 + j;
        float val = acc[fm][fn][j] + bv;
        if (EPI == 2) {
          val = 0.5f * val * (1.0f + erff(val * 0.7071067811865476f));
          ((float*)C)[(size_t)r * N + c] = val;
        } else {
          ((unsigned short*)C)[(size_t)r * N + c] = f2bf(val);
        }
      }
    }
}

// ---- fused scores + softmax + weighted-sum (round-9 proven structure) ------
__global__ __launch_bounds__(256) void k_attn2(
    const unsigned short* __restrict__ xln,   // [2*MROWS][EE]
    unsigned short* qky,                      // [2*BB][HH*EE]  in: qk, out: y
    const int* __restrict__ lastidx) {        // [2*BB]
  __shared__ __align__(16) unsigned short xs[10 * 1544];
  __shared__ float swp[4 * 256];
  __shared__ float wsm[120];
  int b = (BB2 - 1) - blockIdx.x;             // reverse: L3-warm qk first
  int t = threadIdx.x;
  const unsigned short* xg = xln + (size_t)b * SS * EE;
  unsigned short* qg = qky + (size_t)b * HH * EE;
#pragma unroll
  for (int j = 0; j < 8; ++j) {
    int idx = t + j * 256;
    if (idx < 1920) {
      int row = idx / 192, col = (idx - row * 192) * 8;
      *(short8*)(xs + row * 1544 + col) = *(const short8*)(xg + row * 1536 + col);
    }
  }
  __syncthreads();
  int w = t >> 6, lane = t & 63;
  int li = lastidx[b];
  // scores: one 16x16 tile, K=1536 split across 4 waves; A from global qk
  {
    int hr = lane & 15; if (hr > 11) hr = 11;   // A row (head), clamp
    int sr = lane & 15; if (sr > 9) sr = 9;     // B row (seq), clamp
    int kg = lane >> 4;
    f32x4 pacc = (f32x4)0.f;
#pragma unroll 4
    for (int kt = 0; kt < 12; ++kt) {
      int k0 = w * 384 + kt * 32 + kg * 8;
      short8 a  = *(const short8*)(qg + hr * 1536 + k0);
      short8 bf = *(const short8*)(xs + sr * 1544 + k0);
      pacc = __builtin_amdgcn_mfma_f32_16x16x32_bf16(a, bf, pacc, 0, 0, 0);
    }
    int prow = (lane >> 4) * 4, pcol = lane & 15;
#pragma unroll
    for (int j = 0; j < 4; ++j)
      swp[w * 256 + (prow + j) * 16 + pcol] = pacc[j];
  }
  __syncthreads();
  if (t < 120) {
    int h = t / 10, s = t - (t / 10) * 10;
    float v = swp[h * 16 + s] + swp[256 + h * 16 + s] +
              swp[512 + h * 16 + s] + swp[768 + h * 16 + s];
    wsm[t] = v * 0.08838834764831845f;  // HD^-0.5
  }
  __syncthreads();
  if (t < 12) {
    float mx = -1e30f;
    for (int s = 0; s <= li; ++s) mx = fmaxf(mx, wsm[t * 10 + s]);
    float sum = 0.f;
    float ex[SS];
    for (int s = 0; s <= li; ++s) {
      ex[s] = expf(wsm[t * 10 + s] - mx);
      sum += ex[s];
    }
    float inv = 1.0f / sum;
    for (int s = 0; s <= li; ++s) wsm[t * 10 + s] = ex[s] * inv;
  }
  __syncthreads();
  // y phase: wave w handles heads 3w..3w+2; x from LDS, all 10 s-terms
  // unconditional (invalid s has weight 0) -> independent loads.
  float wv[3][10];
#pragma unroll
  for (int hl = 0; hl < 3; ++hl)
#pragma unroll
    for (int s = 0; s < 10; ++s)
      wv[hl][s] = (s <= li) ? wsm[(3 * w + hl) * 10 + s] : 0.f;
#pragma unroll 2
  for (int pass = 0; pass < 12; ++pass) {
    int e0 = pass * 128 + lane * 2;
    unsigned int xr[10];
#pragma unroll
    for (int s = 0; s < 10; ++s)
      xr[s] = *(const unsigned int*)(xs + s * 1544 + e0);
    float acc[3][2] = {};
#pragma unroll
    for (int s = 0; s < 10; ++s) {
      float xlo = bf2f((unsigned short)(xr[s] & 0xffff));
      float xhi = bf2f((unsigned short)(xr[s] >> 16));
#pragma unroll
      for (int hl = 0; hl < 3; ++hl) {
        acc[hl][0] += wv[hl][s] * xlo;
        acc[hl][1] += wv[hl][s] * xhi;
      }
    }
#pragma unroll
    for (int hl = 0; hl < 3; ++hl) {
      unsigned int pk = (unsigned int)f2bf(acc[hl][0]) | ((unsigned int)f2bf(acc[hl][1]) << 16);
      *(unsigned int*)(qg + (3 * w + hl) * 1536 + e0) = pk;
    }
  }
}

extern "C" void kernel_launch(void* const* d_in, const int* in_sizes, int n_in,
                              void* d_out, int out_size, void* d_ws, size_t ws_size,
                              hipStream_t stream) {
  (void)in_sizes; (void)n_in; (void)out_size; (void)ws_size;
  const float* av  = (const float*)d_in[0];
  const float* bv  = (const float*)d_in[1];
  const void*  ma  = d_in[2];
  const void*  mb  = d_in[3];
  const float* qw  = (const float*)d_in[4];
  const float* qb  = (const float*)d_in[5];
  const float* kw  = (const float*)d_in[6];
  const float* kb  = (const float*)d_in[7];  (void)kb;  // softmax-invariant, dropped
  const float* vw  = (const float*)d_in[8];
  const float* vbs = (const float*)d_in[9];
  const float* ow  = (const float*)d_in[10];
  const float* ob  = (const float*)d_in[11];
  const float* fw  = (const float*)d_in[12];
  const float* fbs = (const float*)d_in[13];
  const float* lng = (const float*)d_in[14];
  const float* lnb = (const float*)d_in[15];

  unsigned char* ws = (unsigned char*)d_ws;
  size_t off = 0;
  auto alloc = [&](size_t bytes) {
    size_t r = off; off = (off + bytes + 255) & ~(size_t)255; return (void*)(ws + r);
  };
  int* flags            = (int*)alloc(8);
  float* pe             = (float*)alloc((size_t)SS * EE * 4);
  unsigned short* wt    = (unsigned short*)alloc((size_t)5 * EE * EE * 2);
  unsigned short* kwb   = (unsigned short*)alloc((size_t)EE * EE * 2);   // Wk bf16, [in][out]
  int* lastidx          = (int*)alloc((size_t)BB2 * 4);
  unsigned short* xln   = (unsigned short*)alloc((size_t)MROWS2 * EE * 2);     // 252 MB
  unsigned short* lastx = (unsigned short*)alloc((size_t)BB2 * EE * 2);        // 25 MB
  unsigned short* qbuf  = (unsigned short*)alloc((size_t)BB2 * EE * 2);        // 25 MB
  unsigned short* qky   = (unsigned short*)alloc((size_t)BB2 * HH * EE * 2);   // 302 MB
  unsigned short* ctx   = (unsigned short*)alloc((size_t)BB2 * EE * 2);        // 25 MB
  unsigned short* o1    = (unsigned short*)alloc((size_t)BB2 * EE * 2);        // 25 MB

  unsigned short* wt_q = wt;
  unsigned short* wt_v = wt + (size_t)2 * EE * EE;
  unsigned short* wt_o = wt + (size_t)3 * EE * EE;
  unsigned short* wt_f = wt + (size_t)4 * EE * EE;

  hipMemsetAsync(flags, 0, 8, stream);
  k_detect<<<40, 256, 0, stream>>>((const unsigned int*)ma, flags);
  k_pe<<<(SS * EE + 255) / 256, 256, 0, stream>>>(pe);
  k_trans<<<dim3(EE / 32, EE / 32, 6), dim3(32, 8), 0, stream>>>(qw, kw, vw, ow, fw, wt, kwb);
  k_lastidx<<<(BB2 + 255) / 256, 256, 0, stream>>>(ma, mb, flags, lastidx);

  // fused add-PE + LN, both branches: wave-per-row, 4 rows/block
  k_ln<<<MROWS2 / 4, 256, 0, stream>>>(av, bv, pe, lng, lnb, lastidx, xln, lastx);
  // Q projection: q = lastx @ Wq + qb   [8192 x 1536], 8-phase 256^2
  k_gemm256<0><<<(BB2 / 256) * (EE / 256), 512, 0, stream>>>(
      lastx, wt_q, qb, qbuf, BB2, EE, EE);
  // qk[b,h][e] = sum_d q[b,h,d] * Wk[e, h*128+d]  — single-stage K=128 kernel
  k_gemmqk<<<dim3(64 * 12, HH), 256, 0, stream>>>(qbuf, kwb, qky);
  // scores + softmax + weighted sum -> y (in place over qky), both branches
  k_attn2<<<BB2, 256, 0, stream>>>(xln, qky, lastidx);
  // ctx[b,hblk] = y[b,h] @ Wv[:,hblk] + bv  (per h: [8192x1536]@[1536x128])
  k_gemm_g<<<dim3(64 * 1, HH), 256, 0, stream>>>(
      qky, EE, HH * EE, wt_v, (size_t)0 + HDIM * EE, EE, vbs, HDIM,
      ctx, HDIM, EE, 64, 1, EE);
  // O projection: [8192 x 1536], 8-phase 256^2
  k_gemm256<0><<<(BB2 / 256) * (EE / 256), 512, 0, stream>>>(
      ctx, wt_o, ob, o1, BB2, EE, EE);
  // F projection + exact GELU -> f32 output (branch-major)
  k_gemm256<2><<<(BB2 / 256) * (EE / 256), 512, 0, stream>>>(
      o1, wt_f, fbs, d_out, BB2, EE, EE);
}

// Round 20
// 793.999 us; speedup vs baseline: 1.0627x; 1.0149x over previous
//
#include <hip/hip_runtime.h>
#include <math.h>

#define BB 4096
#define SS 10
#define EE 1536
#define HH 12
#define HDIM 128
#define MROWS (BB * SS)    // 40960 rows per branch
#define BB2 (2 * BB)       // both branches
#define MROWS2 (2 * MROWS)

typedef short short8 __attribute__((ext_vector_type(8)));
typedef float f32x4 __attribute__((ext_vector_type(4)));
typedef const unsigned char __attribute__((address_space(1))) gu8;
typedef unsigned char __attribute__((address_space(3))) lu8;

__device__ __forceinline__ unsigned short f2bf(float x) {
  unsigned int u = __float_as_uint(x);
  return (unsigned short)((u + 0x7FFFu + ((u >> 16) & 1u)) >> 16);
}
__device__ __forceinline__ float bf2f(unsigned short u) {
  return __uint_as_float(((unsigned int)u) << 16);
}

// ---- mask dtype detection (bool bytes vs int32 vs f32), grid-stride --------
__global__ void k_detect(const unsigned int* __restrict__ m, int* __restrict__ flags) {
  int lb = 0, lf = 0;
  int stride = gridDim.x * blockDim.x;
  for (int i = blockIdx.x * blockDim.x + threadIdx.x; i < BB * SS / 4; i += stride) {
    unsigned int wv = m[i];
    if ((wv >> 8) & 0xFFu) lb = 1;
    if (wv >> 16) lf = 1;
  }
  if (lb) atomicOr(&flags[0], 1);
  if (lf) atomicOr(&flags[1], 1);
}

__global__ void k_lastidx(const void* __restrict__ ma, const void* __restrict__ mb,
                          const int* __restrict__ flags, int* __restrict__ lastidx) {
  int idx = blockIdx.x * blockDim.x + threadIdx.x;
  if (idx >= BB2) return;
  const void* m = (idx >= BB) ? mb : ma;
  int b = idx & (BB - 1);
  int f = flags[0] ? 1 : (flags[1] ? 2 : 0);
  int len = 0;
  for (int s = 0; s < SS; ++s) {
    int j = b * SS + s;
    int pad;
    if (f == 1)      pad = ((const unsigned char*)m)[j] != 0;
    else if (f == 2) pad = ((const float*)m)[j] != 0.0f;
    else             pad = ((const int*)m)[j] != 0;
    len += (pad == 0);
  }
  lastidx[idx] = len - 1;
}

// ---- positional-encoding table --------------------------------------------
__global__ void k_pe(float* __restrict__ pe) {
  int idx = blockIdx.x * blockDim.x + threadIdx.x;
  if (idx >= SS * EE) return;
  int s = idx / EE, e = idx - (idx / EE) * EE;
  float fe = (float)(e & ~1);
  float freq = expf(fe * (-9.210340371976184f / (float)EE));  // -ln(10000)/E
  float arg = (float)s * freq;
  pe[idx] = (e & 1) ? cosf(arg) : sinf(arg);
}

// ---- weight transpose f32[K][N] -> bf16[N][K]; z==5: straight cast of kw ---
__global__ void k_trans(const float* __restrict__ w0, const float* __restrict__ w1,
                        const float* __restrict__ w2, const float* __restrict__ w3,
                        const float* __restrict__ w4, unsigned short* __restrict__ wt,
                        unsigned short* __restrict__ kwb) {
  __shared__ float tile[32][33];
  int z = blockIdx.z;
  int n0 = blockIdx.x * 32, k0 = blockIdx.y * 32;
  int tx = threadIdx.x, ty = threadIdx.y;
  if (z == 5) {  // layout-preserving bf16 cast of Wk into kwb
#pragma unroll
    for (int i = 0; i < 4; ++i) {
      size_t idx = (size_t)(k0 + ty + i * 8) * EE + n0 + tx;
      kwb[idx] = f2bf(w1[idx]);
    }
    return;
  }
  const float* W = z == 0 ? w0 : z == 1 ? w1 : z == 2 ? w2 : z == 3 ? w3 : w4;
  unsigned short* T = wt + (size_t)z * EE * EE;
#pragma unroll
  for (int i = 0; i < 4; ++i)
    tile[ty + i * 8][tx] = W[(size_t)(k0 + ty + i * 8) * EE + n0 + tx];
  __syncthreads();
#pragma unroll
  for (int i = 0; i < 4; ++i)
    T[(size_t)(n0 + ty + i * 8) * EE + k0 + tx] = f2bf(tile[tx][ty + i * 8]);
}

// ---- fused add-PE + LayerNorm: wave-per-row, single-pass, no LDS -----------
__global__ __launch_bounds__(256) void k_ln(
    const float* __restrict__ av, const float* __restrict__ bv,
    const float* __restrict__ pe,
    const float* __restrict__ g, const float* __restrict__ be,
    const int* __restrict__ lastidx,
    unsigned short* __restrict__ xln, unsigned short* __restrict__ lastx) {
  int w = threadIdx.x >> 6, lane = threadIdx.x & 63;
  int row = blockIdx.x * 4 + w;               // global row (both branches)
  const float* xin = (row < MROWS) ? (av + (size_t)row * EE)
                                   : (bv + (size_t)(row - MROWS) * EE);
  int bg = row / SS, s = row - bg * SS;       // bg in [0, 2*BB)
  const float4* x4 = (const float4*)xin;
  const float4* p4 = (const float4*)(pe + s * EE);
  float4 v[6];
  float s1 = 0.f, s2 = 0.f;
#pragma unroll
  for (int j = 0; j < 6; ++j) {
    float4 a = x4[j * 64 + lane], p = p4[j * 64 + lane];
    a.x += p.x; a.y += p.y; a.z += p.z; a.w += p.w;
    v[j] = a;
    s1 += a.x + a.y + a.z + a.w;
    s2 += a.x * a.x + a.y * a.y + a.z * a.z + a.w * a.w;
  }
#pragma unroll
  for (int off = 32; off; off >>= 1) {
    s1 += __shfl_xor(s1, off, 64);
    s2 += __shfl_xor(s2, off, 64);
  }
  float mu = s1 * (1.0f / EE);
  float var = s2 * (1.0f / EE) - mu * mu;
  float scl = rsqrtf(var + 1e-5f);
  bool isLast = (s == lastidx[bg]);
  uint2* orow = (uint2*)(xln + (size_t)row * EE);
  uint2* lrow = (uint2*)(lastx + (size_t)bg * EE);
  const float4* g4 = (const float4*)g;
  const float4* b4 = (const float4*)be;
#pragma unroll
  for (int j = 0; j < 6; ++j) {
    int idx = j * 64 + lane;
    float4 gg = g4[idx], bb = b4[idx];
    float o0 = (v[j].x - mu) * scl * gg.x + bb.x;
    float o1 = (v[j].y - mu) * scl * gg.y + bb.y;
    float o2 = (v[j].z - mu) * scl * gg.z + bb.z;
    float o3 = (v[j].w - mu) * scl * gg.w + bb.w;
    uint2 pk;
    pk.x = (unsigned int)f2bf(o0) | ((unsigned int)f2bf(o1) << 16);
    pk.y = (unsigned int)f2bf(o2) | ((unsigned int)f2bf(o3) << 16);
    orow[idx] = pk;
    if (isLast) lrow[idx] = pk;
  }
}

// ---- generalized 128x128 m97-structure bf16 GEMM ---------------------------
__global__ __launch_bounds__(256) void k_gemm_g(
    const unsigned short* __restrict__ A, int aStrH, int lda,
    const unsigned short* __restrict__ Bt, int bStrH, int ldb,
    const float* __restrict__ bias, int biasStrH,
    void* __restrict__ C, int cStrH, int ldc,
    int MB, int NB, int K) {
  __shared__ __align__(16) unsigned char smA[8192];
  __shared__ __align__(16) unsigned char smB[8192];
  int h = blockIdx.y;
  const unsigned char* Ab = (const unsigned char*)(A + (size_t)h * aStrH);
  const unsigned char* Bb = (const unsigned char*)(Bt + (size_t)h * bStrH);
  const float* bi = bias ? bias + (size_t)h * biasStrH : nullptr;
  int per = MB >> 3;
  int bid = blockIdx.x;
  int xcd = bid & 7, lin = bid >> 3;
  int mt = xcd * per + lin / NB;
  int nt = lin % NB;
  int m0 = mt << 7, n0 = nt << 7;
  int tid = threadIdx.x, wid = tid >> 6, lane = tid & 63;
  int wm = wid >> 1, wn = wid & 1;
  f32x4 acc[4][4] = {};
  const size_t ldaB = (size_t)lda * 2, ldbB = (size_t)ldb * 2;
  int lrow = lane & 15, kgrp = lane >> 4;
  int aoff = (wm * 64 + lrow) * 64 + kgrp * 16;
  int boff = (wn * 64 + lrow) * 64 + kgrp * 16;
  int Lbase = wid * 1024 + lane * 16;
  const int nk = K >> 5;
  for (int kt = 0; kt < nk; ++kt) {
    int k0b = kt << 6;
#pragma unroll
    for (int issue = 0; issue < 2; ++issue) {
      int L = issue * 4096 + Lbase;
      int row = L >> 6, colb = L & 63;
      int Lu = issue * 4096 + wid * 1024;
      __builtin_amdgcn_global_load_lds((gu8*)(Ab + (size_t)(m0 + row) * ldaB + k0b + colb),
                                       (lu8*)(smA + Lu), 16, 0, 0);
      __builtin_amdgcn_global_load_lds((gu8*)(Bb + (size_t)(n0 + row) * ldbB + k0b + colb),
                                       (lu8*)(smB + Lu), 16, 0, 0);
    }
    __syncthreads();
    short8 af[4], bfr[4];
#pragma unroll
    for (int i = 0; i < 4; ++i) {
      af[i]  = *(const short8*)(smA + aoff + i * 1024);
      bfr[i] = *(const short8*)(smB + boff + i * 1024);
    }
#pragma unroll
    for (int mi = 0; mi < 4; ++mi)
#pragma unroll
      for (int ni = 0; ni < 4; ++ni)
        acc[mi][ni] = __builtin_amdgcn_mfma_f32_16x16x32_bf16(af[mi], bfr[ni], acc[mi][ni], 0, 0, 0);
    __syncthreads();
  }
  int rbase = m0 + wm * 64 + (lane >> 4) * 4;
  int cbase = n0 + wn * 64 + (lane & 15);
#pragma unroll
  for (int mi = 0; mi < 4; ++mi) {
#pragma unroll
    for (int ni = 0; ni < 4; ++ni) {
      int c = cbase + ni * 16;
      float bv = bi ? bi[c] : 0.f;
#pragma unroll
      for (int j = 0; j < 4; ++j) {
        int r = rbase + mi * 16 + j;
        float val = acc[mi][ni][j] + bv;
        ((unsigned short*)C)[(size_t)h * cStrH + (size_t)r * ldc + c] = f2bf(val);
      }
    }
  }
}

// ---- specialized K=128 single-stage GEMM for the qk projection --------------
__global__ __launch_bounds__(256) void k_gemmqk(
    const unsigned short* __restrict__ A,   // qbuf [BB2][EE]
    const unsigned short* __restrict__ Bt,  // kwb  [EE][EE]
    unsigned short* __restrict__ C) {       // qky  [BB2][HH*EE]
  __shared__ __align__(16) unsigned char smA[32768];
  __shared__ __align__(16) unsigned char smB[32768];
  int h = blockIdx.y;
  int bid = blockIdx.x;
  int xcd = bid & 7, lin = bid >> 3;
  int mt = xcd * 8 + lin / 12;          // M=8192 -> 64 mtiles = 8 xcd x 8
  int nt = lin % 12;                    // N=1536 -> 12 ntiles
  int m0 = mt << 7, n0 = nt << 7;
  int t = threadIdx.x, wid = t >> 6, lane = t & 63;
  const unsigned char* Ab = (const unsigned char*)(A + (size_t)h * HDIM);
  const unsigned char* Bb = (const unsigned char*)(Bt + (size_t)h * HDIM);
  const size_t ldb = (size_t)EE * 2;    // 3072 bytes per row
#pragma unroll
  for (int i = 0; i < 8; ++i) {
    int idx = t + i * 256;
    int row = idx >> 4, slot = idx & 15;
    int srcb = ((slot ^ (row & 7)) << 4);
    int Lu = wid * 1024 + i * 4096;     // wave-uniform; HW adds lane*16
    __builtin_amdgcn_global_load_lds((gu8*)(Ab + (size_t)(m0 + row) * ldb + srcb),
                                     (lu8*)(smA + Lu), 16, 0, 0);
    __builtin_amdgcn_global_load_lds((gu8*)(Bb + (size_t)(n0 + row) * ldb + srcb),
                                     (lu8*)(smB + Lu), 16, 0, 0);
  }
  __syncthreads();
  int wm = wid >> 1, wn = wid & 1;
  int lrow = lane & 15, kgrp = lane >> 4;
  f32x4 acc[4][4] = {};
#pragma unroll
  for (int kk = 0; kk < 4; ++kk) {
    int phys = ((kk * 4 + kgrp) ^ (lrow & 7)) << 4;
    short8 af[4], bfr[4];
#pragma unroll
    for (int i = 0; i < 4; ++i) {
      af[i]  = *(const short8*)(smA + (wm * 64 + i * 16 + lrow) * 256 + phys);
      bfr[i] = *(const short8*)(smB + (wn * 64 + i * 16 + lrow) * 256 + phys);
    }
#pragma unroll
    for (int mi = 0; mi < 4; ++mi)
#pragma unroll
      for (int ni = 0; ni < 4; ++ni)
        acc[mi][ni] = __builtin_amdgcn_mfma_f32_16x16x32_bf16(af[mi], bfr[ni], acc[mi][ni], 0, 0, 0);
  }
  int rbase = m0 + wm * 64 + (lane >> 4) * 4;
  int cbase = n0 + wn * 64 + (lane & 15);
#pragma unroll
  for (int mi = 0; mi < 4; ++mi)
#pragma unroll
    for (int ni = 0; ni < 4; ++ni) {
      int c = cbase + ni * 16;
#pragma unroll
      for (int j = 0; j < 4; ++j) {
        int r = rbase + mi * 16 + j;
        C[(size_t)r * (HH * EE) + (size_t)h * EE + c] = f2bf(acc[mi][ni][j]);
      }
    }
}

// ---- 256x256 8-phase bf16 GEMM (T1+T2+T3+T4+T5) ----------------------------
#define MMAQ(AR_, BR_, QM, QN)                                                  \
  do {                                                                          \
    _Pragma("unroll")                                                           \
    for (int mi_ = 0; mi_ < 4; ++mi_) {                                         \
      _Pragma("unroll")                                                         \
      for (int ni_ = 0; ni_ < 2; ++ni_) {                                       \
        acc[(QM)*4 + mi_][(QN)*2 + ni_] = __builtin_amdgcn_mfma_f32_16x16x32_bf16( \
            AR_[mi_][0], BR_[ni_][0], acc[(QM)*4 + mi_][(QN)*2 + ni_], 0, 0, 0);   \
        acc[(QM)*4 + mi_][(QN)*2 + ni_] = __builtin_amdgcn_mfma_f32_16x16x32_bf16( \
            AR_[mi_][1], BR_[ni_][1], acc[(QM)*4 + mi_][(QN)*2 + ni_], 0, 0, 0);   \
      }                                                                         \
    }                                                                           \
  } while (0)

#define PHASE_MID()                                      \
  do {                                                   \
    __builtin_amdgcn_s_barrier();                        \
    asm volatile("s_waitcnt lgkmcnt(0)" ::: "memory");   \
    __builtin_amdgcn_s_setprio(1);                       \
  } while (0)
#define PHASE_END()                                      \
  do {                                                   \
    __builtin_amdgcn_s_setprio(0);                       \
    __builtin_amdgcn_s_barrier();                        \
  } while (0)

template<int EPI>
__global__ __launch_bounds__(512, 2) void k_gemm256(
    const unsigned short* __restrict__ A, const unsigned short* __restrict__ Bt,
    const float* __restrict__ bias,
    void* __restrict__ C, int M, int N, int K) {
  __shared__ __align__(16) unsigned char lds[131072];
  const int NT = K >> 6;
  const int niters = NT >> 1;
  const int Ntiles = N >> 8;
  const int perx = (M >> 8) >> 3;
  const int MTG = 4;
  int bid = blockIdx.x;
  int xcd = bid & 7, lin = bid >> 3;
  int grp = lin / (MTG * Ntiles);
  int rem = lin - grp * (MTG * Ntiles);
  int nt = rem / MTG, mi_ = rem - nt * MTG;
  int mt = xcd * perx + grp * MTG + mi_;
  int m0 = mt << 8, n0 = nt << 8;
  int tid = threadIdx.x;
  int w = tid >> 6, lane = tid & 63;
  int wm = w >> 2, wn = w & 3;
  const size_t lda = (size_t)K * 2;
  const unsigned char* Ag = (const unsigned char*)A;
  const unsigned char* Bg = (const unsigned char*)Bt;

  unsigned char* A0 = lds;
  unsigned char* B0 = lds + 32768;
  unsigned char* A1 = lds + 65536;
  unsigned char* B1 = lds + 98304;

  int lrows = lane >> 3;
  int colswz = (((lane & 7) ^ (lrows & 7)) << 4);
  int rowA = w * 8;
  int rowB = (w >> 2) * 64 + (w & 3) * 8;

  auto stageA = [&](unsigned char* ldsA, int q, int kt) {
    int cb = kt * 128 + colswz;
#pragma unroll
    for (int i = 0; i < 2; ++i) {
      int tr = q * 64 + i * 128 + rowA;
      __builtin_amdgcn_global_load_lds(
          (gu8*)(Ag + (size_t)(m0 + tr + lrows) * lda + cb),
          (lu8*)(ldsA + tr * 128), 16, 0, 0);
    }
  };
  auto stageB = [&](unsigned char* ldsB, int q, int kt) {
    int cb = kt * 128 + colswz;
#pragma unroll
    for (int i = 0; i < 2; ++i) {
      int tr = q * 32 + i * 128 + rowB;
      __builtin_amdgcn_global_load_lds(
          (gu8*)(Bg + (size_t)(n0 + tr + lrows) * lda + cb),
          (lu8*)(ldsB + tr * 128), 16, 0, 0);
    }
  };

  int lrow = lane & 15, kgrp = lane >> 4, r7 = lane & 7;
  int s0 = ((kgrp ^ r7) << 4), s1 = (((kgrp | 4) ^ r7) << 4);
  int abase = (wm * 128 + lrow) * 128;
  int bbase = (wn * 64 + lrow) * 128;

  short8 ar[4][2], br0[2][2], br1[2][2];
  f32x4 acc[8][4];
#pragma unroll
  for (int i = 0; i < 8; ++i)
#pragma unroll
    for (int j = 0; j < 4; ++j) acc[i][j] = (f32x4)0.f;

  auto ldA = [&](unsigned char* ldsA, int qm) {
#pragma unroll
    for (int mi2 = 0; mi2 < 4; ++mi2) {
      ar[mi2][0] = *(const short8*)(ldsA + abase + qm * 8192 + mi2 * 2048 + s0);
      ar[mi2][1] = *(const short8*)(ldsA + abase + qm * 8192 + mi2 * 2048 + s1);
    }
  };
  auto ldB = [&](unsigned char* ldsB, int qn, short8 (&br)[2][2]) {
#pragma unroll
    for (int ni2 = 0; ni2 < 2; ++ni2) {
      br[ni2][0] = *(const short8*)(ldsB + bbase + qn * 4096 + ni2 * 2048 + s0);
      br[ni2][1] = *(const short8*)(ldsB + bbase + qn * 4096 + ni2 * 2048 + s1);
    }
  };

  stageA(A0, 0, 0); stageB(B0, 0, 0); stageA(A0, 1, 0); stageB(B0, 1, 0);
  stageA(A1, 0, 1); stageB(B1, 0, 1);
  asm volatile("s_waitcnt vmcnt(8)" ::: "memory");
  __builtin_amdgcn_s_barrier();

  for (int it = 0; it < niters - 1; ++it) {
    int t1 = 2 * it + 1, t2 = 2 * it + 2, t3 = 2 * it + 3;
    ldA(A0, 0); ldB(B0, 0, br0);
    stageA(A1, 1, t1);
    asm volatile("s_waitcnt vmcnt(6)" ::: "memory");
    PHASE_MID(); MMAQ(ar, br0, 0, 0); PHASE_END();
    ldB(B0, 1, br1);
    stageB(B1, 1, t1);
    PHASE_MID(); MMAQ(ar, br1, 0, 1); PHASE_END();
    ldA(A0, 1);
    stageA(A0, 0, t2);
    PHASE_MID(); MMAQ(ar, br0, 1, 0); PHASE_END();
    stageB(B0, 0, t2);
    asm volatile("s_waitcnt vmcnt(8)" ::: "memory");
    PHASE_MID(); MMAQ(ar, br1, 1, 1); PHASE_END();
    ldA(A1, 0); ldB(B1, 0, br0);
    stageA(A0, 1, t2);
    asm volatile("s_waitcnt vmcnt(6)" ::: "memory");
    PHASE_MID(); MMAQ(ar, br0, 0, 0); PHASE_END();
    ldB(B1, 1, br1);
    stageB(B0, 1, t2);
    PHASE_MID(); MMAQ(ar, br1, 0, 1); PHASE_END();
    ldA(A1, 1);
    if (t3 < NT) stageA(A1, 0, t3);
    PHASE_MID(); MMAQ(ar, br0, 1, 0); PHASE_END();
    if (t3 < NT) stageB(B1, 0, t3);
    asm volatile("s_waitcnt vmcnt(8)" ::: "memory");
    PHASE_MID(); MMAQ(ar, br1, 1, 1); PHASE_END();
  }
  {
    int t1 = NT - 1;
    ldA(A0, 0); ldB(B0, 0, br0);
    stageA(A1, 1, t1);
    asm volatile("s_waitcnt vmcnt(6)" ::: "memory");
    PHASE_MID(); MMAQ(ar, br0, 0, 0); PHASE_END();
    ldB(B0, 1, br1);
    stageB(B1, 1, t1);
    PHASE_MID(); MMAQ(ar, br1, 0, 1); PHASE_END();
    ldA(A0, 1);
    PHASE_MID(); MMAQ(ar, br0, 1, 0); PHASE_END();
    asm volatile("s_waitcnt vmcnt(4)" ::: "memory");
    PHASE_MID(); MMAQ(ar, br1, 1, 1); PHASE_END();
    ldA(A1, 0); ldB(B1, 0, br0);
    asm volatile("s_waitcnt vmcnt(2)" ::: "memory");
    PHASE_MID(); MMAQ(ar, br0, 0, 0); PHASE_END();
    ldB(B1, 1, br1);
    asm volatile("s_waitcnt vmcnt(0)" ::: "memory");
    PHASE_MID(); MMAQ(ar, br1, 0, 1); PHASE_END();
    ldA(A1, 1);
    PHASE_MID(); MMAQ(ar, br0, 1, 0); PHASE_END();
    PHASE_MID(); MMAQ(ar, br1, 1, 1); PHASE_END();
  }

  int rb = m0 + wm * 128 + (lane >> 4) * 4;
  int cb2 = n0 + wn * 64 + (lane & 15);
#pragma unroll
  for (int fm = 0; fm < 8; ++fm)
#pragma unroll
    for (int fn = 0; fn < 4; ++fn) {
      int c = cb2 + fn * 16;
      float bv = bias[c];
#pragma unroll
      for (int j = 0; j < 4; ++j) {
        int r = rb + fm * 16 + j;
        float val = acc[fm][fn][j] + bv;
        if (EPI == 2) {
          val = 0.5f * val * (1.0f + erff(val * 0.7071067811865476f));
          ((float*)C)[(size_t)r * N + c] = val;
        } else {
          ((unsigned short*)C)[(size_t)r * N + c] = f2bf(val);
        }
      }
    }
}

// ---- fused scores + softmax + weighted-sum (round-9 structure + hoisted
// global A-fragment loads in the score phase) -------------------------------
__global__ __launch_bounds__(256) void k_attn2(
    const unsigned short* __restrict__ xln,   // [2*MROWS][EE]
    unsigned short* qky,                      // [2*BB][HH*EE]  in: qk, out: y
    const int* __restrict__ lastidx) {        // [2*BB]
  __shared__ __align__(16) unsigned short xs[10 * 1544];
  __shared__ float swp[4 * 256];
  __shared__ float wsm[120];
  int b = (BB2 - 1) - blockIdx.x;             // reverse: L3-warm qk first
  int t = threadIdx.x;
  const unsigned short* xg = xln + (size_t)b * SS * EE;
  unsigned short* qg = qky + (size_t)b * HH * EE;
#pragma unroll
  for (int j = 0; j < 8; ++j) {
    int idx = t + j * 256;
    if (idx < 1920) {
      int row = idx / 192, col = (idx - row * 192) * 8;
      *(short8*)(xs + row * 1544 + col) = *(const short8*)(xg + row * 1536 + col);
    }
  }
  __syncthreads();
  int w = t >> 6, lane = t & 63;
  int li = lastidx[b];
  // scores: one 16x16 tile, K=1536 split across 4 waves. The 12 long-latency
  // GLOBAL qk fragment loads are hoisted into registers (independent, issue
  // back-to-back -> one latency exposure); xs fragments stay inline (LDS).
  {
    int hr = lane & 15; if (hr > 11) hr = 11;   // A row (head), clamp
    int sr = lane & 15; if (sr > 9) sr = 9;     // B row (seq), clamp
    int kg = lane >> 4;
    short8 aq[12];
#pragma unroll
    for (int kt = 0; kt < 12; ++kt) {
      int k0 = w * 384 + kt * 32 + kg * 8;
      aq[kt] = *(const short8*)(qg + hr * 1536 + k0);
    }
    f32x4 pacc = (f32x4)0.f;
#pragma unroll
    for (int kt = 0; kt < 12; ++kt) {
      int k0 = w * 384 + kt * 32 + kg * 8;
      short8 bf = *(const short8*)(xs + sr * 1544 + k0);
      pacc = __builtin_amdgcn_mfma_f32_16x16x32_bf16(aq[kt], bf, pacc, 0, 0, 0);
    }
    int prow = (lane >> 4) * 4, pcol = lane & 15;
#pragma unroll
    for (int j = 0; j < 4; ++j)
      swp[w * 256 + (prow + j) * 16 + pcol] = pacc[j];
  }
  __syncthreads();
  if (t < 120) {
    int h = t / 10, s = t - (t / 10) * 10;
    float v = swp[h * 16 + s] + swp[256 + h * 16 + s] +
              swp[512 + h * 16 + s] + swp[768 + h * 16 + s];
    wsm[t] = v * 0.08838834764831845f;  // HD^-0.5
  }
  __syncthreads();
  if (t < 12) {
    float mx = -1e30f;
    for (int s = 0; s <= li; ++s) mx = fmaxf(mx, wsm[t * 10 + s]);
    float sum = 0.f;
    float ex[SS];
    for (int s = 0; s <= li; ++s) {
      ex[s] = expf(wsm[t * 10 + s] - mx);
      sum += ex[s];
    }
    float inv = 1.0f / sum;
    for (int s = 0; s <= li; ++s) wsm[t * 10 + s] = ex[s] * inv;
  }
  __syncthreads();
  // y phase: wave w handles heads 3w..3w+2; x from LDS, all 10 s-terms
  // unconditional (invalid s has weight 0) -> independent loads.
  float wv[3][10];
#pragma unroll
  for (int hl = 0; hl < 3; ++hl)
#pragma unroll
    for (int s = 0; s < 10; ++s)
      wv[hl][s] = (s <= li) ? wsm[(3 * w + hl) * 10 + s] : 0.f;
#pragma unroll 2
  for (int pass = 0; pass < 12; ++pass) {
    int e0 = pass * 128 + lane * 2;
    unsigned int xr[10];
#pragma unroll
    for (int s = 0; s < 10; ++s)
      xr[s] = *(const unsigned int*)(xs + s * 1544 + e0);
    float acc[3][2] = {};
#pragma unroll
    for (int s = 0; s < 10; ++s) {
      float xlo = bf2f((unsigned short)(xr[s] & 0xffff));
      float xhi = bf2f((unsigned short)(xr[s] >> 16));
#pragma unroll
      for (int hl = 0; hl < 3; ++hl) {
        acc[hl][0] += wv[hl][s] * xlo;
        acc[hl][1] += wv[hl][s] * xhi;
      }
    }
#pragma unroll
    for (int hl = 0; hl < 3; ++hl) {
      unsigned int pk = (unsigned int)f2bf(acc[hl][0]) | ((unsigned int)f2bf(acc[hl][1]) << 16);
      *(unsigned int*)(qg + (3 * w + hl) * 1536 + e0) = pk;
    }
  }
}

extern "C" void kernel_launch(void* const* d_in, const int* in_sizes, int n_in,
                              void* d_out, int out_size, void* d_ws, size_t ws_size,
                              hipStream_t stream) {
  (void)in_sizes; (void)n_in; (void)out_size; (void)ws_size;
  const float* av  = (const float*)d_in[0];
  const float* bv  = (const float*)d_in[1];
  const void*  ma  = d_in[2];
  const void*  mb  = d_in[3];
  const float* qw  = (const float*)d_in[4];
  const float* qb  = (const float*)d_in[5];
  const float* kw  = (const float*)d_in[6];
  const float* kb  = (const float*)d_in[7];  (void)kb;  // softmax-invariant, dropped
  const float* vw  = (const float*)d_in[8];
  const float* vbs = (const float*)d_in[9];
  const float* ow  = (const float*)d_in[10];
  const float* ob  = (const float*)d_in[11];
  const float* fw  = (const float*)d_in[12];
  const float* fbs = (const float*)d_in[13];
  const float* lng = (const float*)d_in[14];
  const float* lnb = (const float*)d_in[15];

  unsigned char* ws = (unsigned char*)d_ws;
  size_t off = 0;
  auto alloc = [&](size_t bytes) {
    size_t r = off; off = (off + bytes + 255) & ~(size_t)255; return (void*)(ws + r);
  };
  int* flags            = (int*)alloc(8);
  float* pe             = (float*)alloc((size_t)SS * EE * 4);
  unsigned short* wt    = (unsigned short*)alloc((size_t)5 * EE * EE * 2);
  unsigned short* kwb   = (unsigned short*)alloc((size_t)EE * EE * 2);   // Wk bf16, [in][out]
  int* lastidx          = (int*)alloc((size_t)BB2 * 4);
  unsigned short* xln   = (unsigned short*)alloc((size_t)MROWS2 * EE * 2);     // 252 MB
  unsigned short* lastx = (unsigned short*)alloc((size_t)BB2 * EE * 2);        // 25 MB
  unsigned short* qbuf  = (unsigned short*)alloc((size_t)BB2 * EE * 2);        // 25 MB
  unsigned short* qky   = (unsigned short*)alloc((size_t)BB2 * HH * EE * 2);   // 302 MB
  unsigned short* ctx   = (unsigned short*)alloc((size_t)BB2 * EE * 2);        // 25 MB
  unsigned short* o1    = (unsigned short*)alloc((size_t)BB2 * EE * 2);        // 25 MB

  unsigned short* wt_q = wt;
  unsigned short* wt_v = wt + (size_t)2 * EE * EE;
  unsigned short* wt_o = wt + (size_t)3 * EE * EE;
  unsigned short* wt_f = wt + (size_t)4 * EE * EE;

  hipMemsetAsync(flags, 0, 8, stream);
  k_detect<<<40, 256, 0, stream>>>((const unsigned int*)ma, flags);
  k_pe<<<(SS * EE + 255) / 256, 256, 0, stream>>>(pe);
  k_trans<<<dim3(EE / 32, EE / 32, 6), dim3(32, 8), 0, stream>>>(qw, kw, vw, ow, fw, wt, kwb);
  k_lastidx<<<(BB2 + 255) / 256, 256, 0, stream>>>(ma, mb, flags, lastidx);

  // fused add-PE + LN, both branches: wave-per-row, 4 rows/block
  k_ln<<<MROWS2 / 4, 256, 0, stream>>>(av, bv, pe, lng, lnb, lastidx, xln, lastx);
  // Q projection: q = lastx @ Wq + qb   [8192 x 1536], 8-phase 256^2
  k_gemm256<0><<<(BB2 / 256) * (EE / 256), 512, 0, stream>>>(
      lastx, wt_q, qb, qbuf, BB2, EE, EE);
  // qk[b,h][e] = sum_d q[b,h,d] * Wk[e, h*128+d]  — single-stage K=128 kernel
  k_gemmqk<<<dim3(64 * 12, HH), 256, 0, stream>>>(qbuf, kwb, qky);
  // scores + softmax + weighted sum -> y (in place over qky), both branches
  k_attn2<<<BB2, 256, 0, stream>>>(xln, qky, lastidx);
  // ctx[b,hblk] = y[b,h] @ Wv[:,hblk] + bv  (per h: [8192x1536]@[1536x128])
  k_gemm_g<<<dim3(64 * 1, HH), 256, 0, stream>>>(
      qky, EE, HH * EE, wt_v, (size_t)0 + HDIM * EE, EE, vbs, HDIM,
      ctx, HDIM, EE, 64, 1, EE);
  // O projection: [8192 x 1536], 8-phase 256^2
  k_gemm256<0><<<(BB2 / 256) * (EE / 256), 512, 0, stream>>>(
      ctx, wt_o, ob, o1, BB2, EE, EE);
  // F projection + exact GELU -> f32 output (branch-major)
  k_gemm256<2><<<(BB2 / 256) * (EE / 256), 512, 0, stream>>>(
      o1, wt_f, fbs, d_out, BB2, EE, EE);
}